// Round 16
// baseline (407.800 us; speedup 1.0000x reference)
//
#include <hip/hip_runtime.h>
#include <hip/hip_bf16.h>

// Classifier_69818988363910:
//   F = mean_pool_J30(relu(x @ W1^T))                [2000, 2048]
//   logits = F @ (Wlin[:, :2048]+Wlin[:, 2048:])^T   [2000, 1000]
// (y, W2 are dead per the reference's own bug; features2 == features)

typedef __attribute__((ext_vector_type(4))) float f32x4;
typedef __attribute__((ext_vector_type(16))) float f32x16;
typedef __attribute__((ext_vector_type(8))) short short8;

__device__ __forceinline__ unsigned short f2bf(float f) {
  unsigned int u = __float_as_uint(f);
  unsigned int r = (u + 0x7fffu + ((u >> 16) & 1u)) >> 16;
  return (unsigned short)r;
}

__device__ __forceinline__ unsigned long long pack4(f32x4 v) {
  return (unsigned long long)f2bf(v.x)
       | ((unsigned long long)f2bf(v.y) << 16)
       | ((unsigned long long)f2bf(v.z) << 32)
       | ((unsigned long long)f2bf(v.w) << 48);
}

__device__ __forceinline__ void gload_lds16(const unsigned short* gp, unsigned short* lp) {
  __builtin_amdgcn_global_load_lds((const __attribute__((address_space(1))) void*)gp,
                                   (__attribute__((address_space(3))) void*)lp, 16, 0, 0);
}

__global__ void cvt_f32_bf16(const float* __restrict__ src,
                             unsigned short* __restrict__ dst, int n4) {
  int i = blockIdx.x * 256 + threadIdx.x;
  if (i >= n4) return;
  f32x4 v = *(const f32x4*)(src + (size_t)i * 4);
  *(unsigned long long*)(dst + (size_t)i * 4) = pack4(v);
}

// merged: wsum prep (items 0..511999) + W1 f32->bf16 (next 524288 items)
__global__ void prep_w(const float* __restrict__ wlin,
                       const float* __restrict__ w1,
                       unsigned short* __restrict__ wsum,
                       unsigned short* __restrict__ w1b) {
  int i = blockIdx.x * 256 + threadIdx.x;
  if (i < 1000 * 512) {
    int c = i >> 9, f4 = i & 511;
    const float* p0 = wlin + (size_t)c * 4096 + f4 * 4;
    f32x4 a = *(const f32x4*)p0;
    f32x4 b = *(const f32x4*)(p0 + 2048);
    f32x4 s = a + b;
    *(unsigned long long*)(wsum + (size_t)c * 2048 + f4 * 4) = pack4(s);
  } else {
    int j = i - 1000 * 512;
    if (j < 2048 * 256) {
      f32x4 v = *(const f32x4*)(w1 + (size_t)j * 4);
      *(unsigned long long*)(w1b + (size_t)j * 4) = pack4(v);
    }
  }
}

__global__ void prep_wsum(const float* __restrict__ wlin,
                          unsigned short* __restrict__ dst) {
  int i = blockIdx.x * 256 + threadIdx.x;
  if (i >= 1000 * 512) return;
  int c = i >> 9, f4 = i & 511;
  const float* p0 = wlin + (size_t)c * 4096 + f4 * 4;
  f32x4 a = *(const f32x4*)p0;
  f32x4 b = *(const f32x4*)(p0 + 2048);
  f32x4 s = a + b;
  *(unsigned long long*)(dst + (size_t)c * 2048 + f4 * 4) = pack4(s);
}

// ---------------------------------------------------------------------------
// GEMM1: 8-phase schedule, 256x256 tile, BK=64 as 2 K-halves of 32, 2 dbuf
// slot-pairs per matrix (128 KB), counted-vmcnt (R8 ledger), R3-form swizzle,
// single trailing barrier per phase (R11), fine interleave (R15).
// R16: MFMA shape 16x16x32 -> 32x32x16. Same operand regs (4+4 VGPR) but 2x
// FLOP/instr and ~15% faster ubench (2382 vs 2075 TF): halves MFMA-pipe issue
// demand per phase (8 instr vs 16) with IDENTICAL LDS traffic and staging.
// Frag layouts: A/B row=lane&31, k-off=(lane>>5)*8 (same generalization as
// the verified 16x16 reads); C/D col=lane&31, row=(reg&3)+8*(reg>>2)+
// 4*(lane>>5) [m74/m101]. Bank check: lanes cover all 8 16B-slots exactly
// 8x under chunk^((row>>1)&3) -> conflict-free (unchanged).
// ---------------------------------------------------------------------------
#define WAITV(n) asm volatile("s_waitcnt vmcnt(" #n ")" ::: "memory")
#define CFENCE() asm volatile("" ::: "memory")

__global__ __launch_bounds__(512, 2)
void gemm256_pool(const unsigned short* __restrict__ A,
                  const unsigned short* __restrict__ B,
                  unsigned short* __restrict__ feat,
                  int Mv, int K) {
  __shared__ __align__(16) unsigned short smem[65536];  // 128 KB

  const int tid = threadIdx.x;
  const int lane = tid & 63;
  const int w = tid >> 6;          // 0..7
  const int wr = w >> 2;           // 0..1  (M half, 128 rows)
  const int wc = w & 3;            // 0..3  (N quarter, 64 cols)

  // XCD-chunked bijective swizzle: 2000 blocks, 8 XCDs, 250 each.
  const int bid = blockIdx.x;
  const int swz = (bid & 7) * 250 + (bid >> 3);
  const int by = swz >> 3;         // 0..249  M-block
  const int bx = swz & 7;          // 0..7    N-block
  const int bm0 = by * 240;
  const int bn0 = bx * 256;
  const int NT2 = K >> 6;          // K-steps of 64 (=16)
  const int NI = NT2 >> 1;         // iterations (=8)

  // staging: identical to R15 (lane covers row base+(lane>>2), phys chunk
  // lane&3; pre-swizzled logical k-chunk = (lane&3) ^ ((lane>>3)&3)).
  const int kslot = (((lane & 3) ^ ((lane >> 3) & 3)) * 8);
  int rA0 = bm0 + w * 32 + 0 + (lane >> 2);  if (rA0 >= Mv) rA0 = Mv - 1;
  int rA1 = bm0 + w * 32 + 16 + (lane >> 2); if (rA1 >= Mv) rA1 = Mv - 1;
  const int rB0 = bn0 + w * 32 + 0 + (lane >> 2);
  const int rB1 = bn0 + w * 32 + 16 + (lane >> 2);
  const unsigned short* gA0 = A + (size_t)rA0 * K + kslot;
  const unsigned short* gA1 = A + (size_t)rA1 * K + kslot;
  const unsigned short* gB0 = B + (size_t)rB0 * K + kslot;
  const unsigned short* gB1 = B + (size_t)rB1 * K + kslot;

// slots: A half (S,KS) at ((S)*2+(KS))*8192 shorts; B at +32768
#define STAGE_A(tt, S, KS) do {                                          \
    const size_t _ko = (size_t)(((tt) < NT2) ? (tt) : (NT2 - 1)) * 64 +  \
                       (KS) * 32;                                        \
    gload_lds16(gA0 + _ko, smem + ((S)*2+(KS))*8192 + w * 1024);         \
    gload_lds16(gA1 + _ko, smem + ((S)*2+(KS))*8192 + w * 1024 + 512);   \
  } while (0)
#define STAGE_B(tt, S, KS) do {                                          \
    const size_t _ko = (size_t)(((tt) < NT2) ? (tt) : (NT2 - 1)) * 64 +  \
                       (KS) * 32;                                        \
    gload_lds16(gB0 + _ko, smem + 32768 + ((S)*2+(KS))*8192 + w * 1024); \
    gload_lds16(gB1 + _ko, smem + 32768 + ((S)*2+(KS))*8192 + w * 1024 + 512); \
  } while (0)

  // per-wave output 128x64 = 4 Mtiles x 2 Ntiles of 32x32
  f32x16 acc[4][2];
#pragma unroll
  for (int i = 0; i < 4; ++i)
#pragma unroll
    for (int j = 0; j < 2; ++j)
#pragma unroll
      for (int r = 0; r < 16; ++r) acc[i][j][r] = 0.f;

  // fragment reads (32x32x16): row = lane&31, k-off = (lane>>5)*8.
  // LDS chunk(s) = ((2*s + c0) ^ xr) * 8 shorts, xr = swizzle bits of row.
  const int rl = lane & 31;
  const int c0 = lane >> 5;
  const int xr = (lane >> 1) & 3;           // ((row>>1)&3) with row = base+rl
  const int ck0 = ((c0) ^ xr) * 8;          // kstep 0
  const int ck1 = ((2 + c0) ^ xr) * 8;      // kstep 1
#define LDA(S, KS, M, CK) (*(const short8*)(smem + ((S)*2+(KS))*8192 +   \
    (wr * 128 + (M) * 32 + rl) * 32 + (CK)))
#define LDB(S, KS, N, CK) (*(const short8*)(smem + 32768 +               \
    ((S)*2+(KS))*8192 + (wc * 64 + (N) * 32 + rl) * 32 + (CK)))

  short8 bfr00, bfr01, bfr10, bfr11;  // (Ntile, kstep)

#define MFMA32(AF, BF, ACC) ACC = __builtin_amdgcn_mfma_f32_32x32x16_bf16( \
    AF, BF, ACC, 0, 0, 0)

  // PHASE: stage first; fine read/MFMA interleave; trailing counted vmcnt +
  // single barrier. Cross-barrier memory-op order identical to R11/R15.
#define PHASE(S, KS, IH, DOB, TRAILVM, STG) do {                         \
    STG;                                                                 \
    if (DOB) {                                                           \
      bfr00 = LDB(S, KS, 0, ck0); bfr01 = LDB(S, KS, 0, ck1);            \
      bfr10 = LDB(S, KS, 1, ck0); bfr11 = LDB(S, KS, 1, ck1);            \
    }                                                                    \
    short8 a00 = LDA(S, KS, (IH)*2 + 0, ck0);                            \
    short8 a01 = LDA(S, KS, (IH)*2 + 0, ck1);                            \
    __builtin_amdgcn_s_setprio(1);                                       \
    short8 a10 = LDA(S, KS, (IH)*2 + 1, ck0);                            \
    MFMA32(a00, bfr00, acc[(IH)*2][0]);                                  \
    MFMA32(a00, bfr10, acc[(IH)*2][1]);                                  \
    short8 a11 = LDA(S, KS, (IH)*2 + 1, ck1);                            \
    MFMA32(a01, bfr01, acc[(IH)*2][0]);                                  \
    MFMA32(a01, bfr11, acc[(IH)*2][1]);                                  \
    MFMA32(a10, bfr00, acc[(IH)*2+1][0]);                                \
    MFMA32(a10, bfr10, acc[(IH)*2+1][1]);                                \
    MFMA32(a11, bfr01, acc[(IH)*2+1][0]);                                \
    MFMA32(a11, bfr11, acc[(IH)*2+1][1]);                                \
    __builtin_amdgcn_s_setprio(0);                                       \
    CFENCE();                                                            \
    if (TRAILVM) { WAITV(10); }                                          \
    CFENCE();                                                            \
    __builtin_amdgcn_s_barrier();                                        \
  } while (0)

  // ---- prologue: 7 half-tiles (14 loads/thread), FIFO order matters ----
  STAGE_B(0, 0, 0); STAGE_A(0, 0, 0); STAGE_B(0, 0, 1); STAGE_A(0, 0, 1);
  STAGE_B(1, 1, 0); STAGE_A(1, 1, 0); STAGE_B(1, 1, 1);
  WAITV(10);                        // drain B(0,0), A(0,0)
  CFENCE();
  __builtin_amdgcn_s_barrier();     // all waves drained -> p0 reads are safe

  for (int j = 0; j < NI; ++j) {
    const int t0 = 2 * j, t1 = 2 * j + 1;
    PHASE(0, 0, 0, 1, 0, STAGE_A(t1,     1, 1));  // p0
    PHASE(0, 0, 1, 0, 1, STAGE_B(t0 + 2, 0, 0));  // p1 (drain for p2)
    PHASE(0, 1, 0, 1, 0, STAGE_A(t0 + 2, 0, 0));  // p2
    PHASE(0, 1, 1, 0, 1, STAGE_B(t0 + 2, 0, 1));  // p3 (drain for p4)
    PHASE(1, 0, 0, 1, 0, STAGE_A(t0 + 2, 0, 1));  // p4
    PHASE(1, 0, 1, 0, 1, STAGE_B(t1 + 2, 1, 0));  // p5 (drain for p6)
    PHASE(1, 1, 0, 1, 0, STAGE_A(t1 + 2, 1, 0));  // p6
    PHASE(1, 1, 1, 0, 1, STAGE_B(t1 + 2, 1, 1));  // p7 (drain for next p0)
  }

  // drain pending (clamped) tail stages before panel reuse
  WAITV(0);
  CFENCE();
  __builtin_amdgcn_s_barrier();

  // ---- epilogue: relu + J=30 mean pool via padded f32 [256][65] panel ----
  // C/D mapping (32x32): col = lane&31, row = (r&3) + 8*(r>>2) + 4*(lane>>5)
  float* panel = (float*)smem;      // 66560 B <= 128 KB
#pragma unroll 1
  for (int c = 0; c < 4; ++c) {
    if (wc == c) {
#pragma unroll
      for (int m = 0; m < 4; ++m)
#pragma unroll
        for (int n = 0; n < 2; ++n)
#pragma unroll
          for (int r = 0; r < 16; ++r)
            panel[(wr * 128 + m * 32 + (r & 3) + 8 * (r >> 2) + 4 * c0) * 65 +
                  n * 32 + rl] = fmaxf(acc[m][n][r], 0.f);
    }
    __builtin_amdgcn_s_barrier();
    CFENCE();
    {
      int col = tid & 63;
      int s = tid >> 6;
      float sum = 0.f;
#pragma unroll
      for (int r = 0; r < 30; ++r) sum += panel[(s * 30 + r) * 65 + col];
      int gseg = by * 8 + s;
      int gcol = bn0 + c * 64 + col;
      feat[(size_t)gseg * 2048 + gcol] = f2bf(sum * (1.f / 30.f));
    }
    CFENCE();
    __builtin_amdgcn_s_barrier();
  }
#undef PHASE
#undef MFMA32
#undef LDA
#undef LDB
#undef STAGE_A
#undef STAGE_B
}

// ---------------------------------------------------------------------------
// 128x128 kernel: GEMM2 (MODE 2) and the no-workspace fallback (MODE 0).
// ---------------------------------------------------------------------------
#define BM 128
#define BN 128
#define BK 64

template<int MODE>
__global__ __launch_bounds__(256, 2)
void gemm_bt(const void* __restrict__ Ap, const void* __restrict__ Bp,
             void* __restrict__ Cp, int Mv, int Nv, int K, int mstep) {
  constexpr int LDK = (MODE == 0) ? 72 : 64;
  __shared__ __align__(16) unsigned short smem[2 * BM * LDK];
  unsigned short* As = smem;
  unsigned short* Bs = smem + BM * LDK;
  float* Cs = (float*)smem;

  const int tid = threadIdx.x;
  const int lane = tid & 63;
  const int w = tid >> 6;
  const int wr = w >> 1, wc = w & 1;
  const int bm0 = blockIdx.y * mstep;
  const int bn0 = blockIdx.x * BN;

  f32x4 acc[4][4];
#pragma unroll
  for (int i = 0; i < 4; ++i)
#pragma unroll
    for (int j = 0; j < 4; ++j) acc[i][j] = (f32x4){0.f, 0.f, 0.f, 0.f};

  const int fr = lane & 15;
  const int ko = (lane >> 4) * 8;

  for (int kt = 0; kt < K; kt += BK) {
    __syncthreads();
    if constexpr (MODE == 0) {
      const float* A = (const float*)Ap;
      const float* B = (const float*)Bp;
      const int r0 = tid >> 4, kq = tid & 15;
#pragma unroll
      for (int i = 0; i < 8; ++i) {
        int row = i * 16 + r0;
        {
          int gm = bm0 + row;
          f32x4 v = {0.f, 0.f, 0.f, 0.f};
          if (gm < Mv) v = *(const f32x4*)(A + (size_t)gm * K + kt + kq * 4);
          *(unsigned long long*)(As + row * LDK + kq * 4) = pack4(v);
        }
        {
          int gn = bn0 + row;
          f32x4 v = {0.f, 0.f, 0.f, 0.f};
          if (gn < Nv) v = *(const f32x4*)(B + (size_t)gn * K + kt + kq * 4);
          *(unsigned long long*)(Bs + row * LDK + kq * 4) = pack4(v);
        }
      }
    } else {
      const unsigned short* A = (const unsigned short*)Ap;
      const unsigned short* B = (const unsigned short*)Bp;
      const int rsub = lane >> 3;
      const int k8 = (((lane & 7) ^ (lane >> 3)) * 8);
#pragma unroll
      for (int j = 0; j < 4; ++j) {
        int g = w * 4 + j;
        int row = g * 8 + rsub;
        int gm = bm0 + row; if (gm >= Mv) gm = Mv - 1;
        gload_lds16(A + (size_t)gm * K + kt + k8, As + g * 512);
        int gn = bn0 + row; if (gn >= Nv) gn = Nv - 1;
        gload_lds16(B + (size_t)gn * K + kt + k8, Bs + g * 512);
      }
    }
    __syncthreads();
#pragma unroll
    for (int kk = 0; kk < 2; ++kk) {
      const int coffA = (MODE == 0) ? (kk * 32 + ko)
                                    : ((((kk << 2) | (lane >> 4)) ^ (fr & 7)) * 8);
      short8 af[4], bfr[4];
#pragma unroll
      for (int i = 0; i < 4; ++i)
        af[i] = *(const short8*)(As + (wr * 64 + i * 16 + fr) * LDK + coffA);
#pragma unroll
      for (int i = 0; i < 4; ++i)
        bfr[i] = *(const short8*)(Bs + (wc * 64 + i * 16 + fr) * LDK + coffA);
#pragma unroll
      for (int i = 0; i < 4; ++i)
#pragma unroll
        for (int j = 0; j < 4; ++j)
          acc[i][j] = __builtin_amdgcn_mfma_f32_16x16x32_bf16(af[i], bfr[j], acc[i][j], 0, 0, 0);
    }
  }
  __syncthreads();

  if constexpr (MODE != 2) {
    unsigned short* feat = (unsigned short*)Cp;
    const int cr0 = (lane >> 4) * 4;
#pragma unroll
    for (int half = 0; half < 2; ++half) {
      if (wc == half) {
#pragma unroll
        for (int i = 0; i < 4; ++i)
#pragma unroll
          for (int j = 0; j < 4; ++j)
#pragma unroll
            for (int r = 0; r < 4; ++r)
              Cs[(wr * 64 + i * 16 + cr0 + r) * 64 + j * 16 + fr] =
                  fmaxf(acc[i][j][r], 0.f);
      }
      __syncthreads();
      {
        int col = tid & 63;
        int s = tid >> 6;
        float sum = 0.f;
#pragma unroll
        for (int r = 0; r < 30; ++r) sum += Cs[(s * 30 + r) * 64 + col];
        int gseg = blockIdx.y * 4 + s;
        int gcol = bn0 + half * 64 + col;
        feat[(size_t)gseg * 2048 + gcol] = f2bf(sum * (1.f / 30.f));
      }
      __syncthreads();
    }
  } else {
    float* out = (float*)Cp;
    const int cr0 = (lane >> 4) * 4;
#pragma unroll
    for (int i = 0; i < 4; ++i)
#pragma unroll
      for (int j = 0; j < 4; ++j)
#pragma unroll
        for (int r = 0; r < 4; ++r) {
          int gm = bm0 + wr * 64 + i * 16 + cr0 + r;
          int gn = bn0 + wc * 64 + j * 16 + fr;
          if (gm < Mv && gn < Nv) out[(size_t)gm * Nv + gn] = acc[i][j][r];
        }
  }
}

extern "C" void kernel_launch(void* const* d_in, const int* in_sizes, int n_in,
                              void* d_out, int out_size, void* d_ws, size_t ws_size,
                              hipStream_t stream) {
  const float* x    = (const float*)d_in[0];
  const float* W1   = (const float*)d_in[2];
  const float* Wlin = (const float*)d_in[4];
  float* out = (float*)d_out;

  const int T = 60000, DIN = 1024, E = 2048, C = 1000, S = 2000;
  char* ws = (char*)d_ws;
  const size_t off_feat = 0;
  const size_t off_wsum = (size_t)S * E * 2;
  const size_t off_w1b  = off_wsum + (size_t)C * E * 2;
  const size_t off_xb   = off_w1b + (size_t)E * DIN * 2;
  const size_t need_full = off_xb + (size_t)T * DIN * 2;   // ~139.4 MB

  unsigned short* feat = (unsigned short*)(ws + off_feat);
  unsigned short* wsum = (unsigned short*)(ws + off_wsum);

  if (ws_size >= need_full) {
    unsigned short* w1b = (unsigned short*)(ws + off_w1b);
    unsigned short* xb  = (unsigned short*)(ws + off_xb);
    // merged wsum + W1-cvt: 512000 + 524288 items
    prep_w<<<dim3((1000 * 512 + 2048 * 256 + 255) / 256), dim3(256), 0, stream>>>(
        Wlin, W1, wsum, w1b);
    int nx4 = T * DIN / 4;
    cvt_f32_bf16<<<dim3((nx4 + 255) / 256), dim3(256), 0, stream>>>(x, xb, nx4);
    gemm256_pool<<<dim3(2000), dim3(512), 0, stream>>>(xb, w1b, feat, T, DIN);
  } else {
    prep_wsum<<<dim3((C * E / 4 + 255) / 256), dim3(256), 0, stream>>>(Wlin, wsum);
    gemm_bt<0><<<dim3(16, 500), dim3(256), 0, stream>>>(x, W1, feat, T, E, DIN, 120);
  }

  gemm_bt<2><<<dim3(8, 16), dim3(256), 0, stream>>>(feat, wsum, out, S, C, E, 128);
}

// Round 17
// 358.455 us; speedup vs baseline: 1.1377x; 1.1377x over previous
//
#include <hip/hip_runtime.h>
#include <hip/hip_bf16.h>

// Classifier_69818988363910:
//   F = mean_pool_J30(relu(x @ W1^T))                [2000, 2048]
//   logits = F @ (Wlin[:, :2048]+Wlin[:, 2048:])^T   [2000, 1000]
// (y, W2 are dead per the reference's own bug; features2 == features)

typedef __attribute__((ext_vector_type(4))) float f32x4;
typedef __attribute__((ext_vector_type(8))) short short8;

__device__ __forceinline__ unsigned short f2bf(float f) {
  unsigned int u = __float_as_uint(f);
  unsigned int r = (u + 0x7fffu + ((u >> 16) & 1u)) >> 16;
  return (unsigned short)r;
}

__device__ __forceinline__ unsigned long long pack4(f32x4 v) {
  return (unsigned long long)f2bf(v.x)
       | ((unsigned long long)f2bf(v.y) << 16)
       | ((unsigned long long)f2bf(v.z) << 32)
       | ((unsigned long long)f2bf(v.w) << 48);
}

__device__ __forceinline__ void gload_lds16(const unsigned short* gp, unsigned short* lp) {
  __builtin_amdgcn_global_load_lds((const __attribute__((address_space(1))) void*)gp,
                                   (__attribute__((address_space(3))) void*)lp, 16, 0, 0);
}

__global__ void cvt_f32_bf16(const float* __restrict__ src,
                             unsigned short* __restrict__ dst, int n4) {
  int i = blockIdx.x * 256 + threadIdx.x;
  if (i >= n4) return;
  f32x4 v = *(const f32x4*)(src + (size_t)i * 4);
  *(unsigned long long*)(dst + (size_t)i * 4) = pack4(v);
}

// merged: wsum prep (items 0..511999) + W1 f32->bf16 (next 524288 items)
__global__ void prep_w(const float* __restrict__ wlin,
                       const float* __restrict__ w1,
                       unsigned short* __restrict__ wsum,
                       unsigned short* __restrict__ w1b) {
  int i = blockIdx.x * 256 + threadIdx.x;
  if (i < 1000 * 512) {
    int c = i >> 9, f4 = i & 511;
    const float* p0 = wlin + (size_t)c * 4096 + f4 * 4;
    f32x4 a = *(const f32x4*)p0;
    f32x4 b = *(const f32x4*)(p0 + 2048);
    f32x4 s = a + b;
    *(unsigned long long*)(wsum + (size_t)c * 2048 + f4 * 4) = pack4(s);
  } else {
    int j = i - 1000 * 512;
    if (j < 2048 * 256) {
      f32x4 v = *(const f32x4*)(w1 + (size_t)j * 4);
      *(unsigned long long*)(w1b + (size_t)j * 4) = pack4(v);
    }
  }
}

__global__ void prep_wsum(const float* __restrict__ wlin,
                          unsigned short* __restrict__ dst) {
  int i = blockIdx.x * 256 + threadIdx.x;
  if (i >= 1000 * 512) return;
  int c = i >> 9, f4 = i & 511;
  const float* p0 = wlin + (size_t)c * 4096 + f4 * 4;
  f32x4 a = *(const f32x4*)p0;
  f32x4 b = *(const f32x4*)(p0 + 2048);
  f32x4 s = a + b;
  *(unsigned long long*)(dst + (size_t)c * 2048 + f4 * 4) = pack4(s);
}

// out = slab0 + slab1, 2e6 f32, vectorized x4
__global__ void reduce2(const float* __restrict__ s0,
                        const float* __restrict__ s1,
                        float* __restrict__ out, int n4) {
  int i = blockIdx.x * 256 + threadIdx.x;
  if (i >= n4) return;
  f32x4 a = *(const f32x4*)(s0 + (size_t)i * 4);
  f32x4 b = *(const f32x4*)(s1 + (size_t)i * 4);
  f32x4 s = a + b;
  *(f32x4*)(out + (size_t)i * 4) = s;
}

// ---------------------------------------------------------------------------
// GEMM1: R15 exact (best measured: 274.6us, MfmaUtil 44.3%). 8-phase, 256x256
// tile, BK=64 as 2 K-halves, counted-vmcnt, R3-form swizzle, single trailing
// barrier per phase, fine ds_read/MFMA interleave. R16's 32x32-shape attempt
// regressed (conflicts 6x up) and is reverted.
// ---------------------------------------------------------------------------
#define WAITV(n) asm volatile("s_waitcnt vmcnt(" #n ")" ::: "memory")
#define CFENCE() asm volatile("" ::: "memory")

__global__ __launch_bounds__(512, 2)
void gemm256_pool(const unsigned short* __restrict__ A,
                  const unsigned short* __restrict__ B,
                  unsigned short* __restrict__ feat,
                  int Mv, int K) {
  __shared__ __align__(16) unsigned short smem[65536];  // 128 KB

  const int tid = threadIdx.x;
  const int lane = tid & 63;
  const int w = tid >> 6;          // 0..7
  const int wr = w >> 2;           // 0..1  (M half)
  const int wc = w & 3;            // 0..3  (N quarter)

  const int bid = blockIdx.x;
  const int swz = (bid & 7) * 250 + (bid >> 3);
  const int by = swz >> 3;         // 0..249  M-block
  const int bx = swz & 7;          // 0..7    N-block
  const int bm0 = by * 240;
  const int bn0 = bx * 256;
  const int NT2 = K >> 6;          // K-steps of 64 (=16)
  const int NI = NT2 >> 1;         // iterations (=8)

  const int kslot = (((lane & 3) ^ ((lane >> 3) & 3)) * 8);
  int rA0 = bm0 + w * 32 + 0 + (lane >> 2);  if (rA0 >= Mv) rA0 = Mv - 1;
  int rA1 = bm0 + w * 32 + 16 + (lane >> 2); if (rA1 >= Mv) rA1 = Mv - 1;
  const int rB0 = bn0 + w * 32 + 0 + (lane >> 2);
  const int rB1 = bn0 + w * 32 + 16 + (lane >> 2);
  const unsigned short* gA0 = A + (size_t)rA0 * K + kslot;
  const unsigned short* gA1 = A + (size_t)rA1 * K + kslot;
  const unsigned short* gB0 = B + (size_t)rB0 * K + kslot;
  const unsigned short* gB1 = B + (size_t)rB1 * K + kslot;

#define STAGE_A(tt, S, KS) do {                                          \
    const size_t _ko = (size_t)(((tt) < NT2) ? (tt) : (NT2 - 1)) * 64 +  \
                       (KS) * 32;                                        \
    gload_lds16(gA0 + _ko, smem + ((S)*2+(KS))*8192 + w * 1024);         \
    gload_lds16(gA1 + _ko, smem + ((S)*2+(KS))*8192 + w * 1024 + 512);   \
  } while (0)
#define STAGE_B(tt, S, KS) do {                                          \
    const size_t _ko = (size_t)(((tt) < NT2) ? (tt) : (NT2 - 1)) * 64 +  \
                       (KS) * 32;                                        \
    gload_lds16(gB0 + _ko, smem + 32768 + ((S)*2+(KS))*8192 + w * 1024); \
    gload_lds16(gB1 + _ko, smem + 32768 + ((S)*2+(KS))*8192 + w * 1024 + 512); \
  } while (0)

  f32x4 acc[8][4];
#pragma unroll
  for (int i = 0; i < 8; ++i)
#pragma unroll
    for (int j = 0; j < 4; ++j) acc[i][j] = (f32x4){0.f, 0.f, 0.f, 0.f};

  const int fr = lane & 15;
  const int qa8 = (((lane >> 4) ^ ((fr >> 1) & 3)) * 8);
#define LDA(S, KS, I) (*(const short8*)(smem + ((S)*2+(KS))*8192 +       \
    (wr * 128 + (I) * 16 + fr) * 32 + qa8))
#define LDB(S, KS, J) (*(const short8*)(smem + 32768 + ((S)*2+(KS))*8192 + \
    (wc * 64 + (J) * 16 + fr) * 32 + qa8))

  short8 bfr[4];

#define CLUSTER(ROW, AF)                                                  \
    _Pragma("unroll") for (int jj = 0; jj < 4; ++jj)                      \
      acc[ROW][jj] = __builtin_amdgcn_mfma_f32_16x16x32_bf16(             \
          AF, bfr[jj], acc[ROW][jj], 0, 0, 0)

#define PHASE(S, KS, IH, DOB, TRAILVM, STG) do {                         \
    STG;                                                                 \
    short8 afr0, afr1, afr2, afr3;                                       \
    if (DOB) {                                                           \
      _Pragma("unroll") for (int jj = 0; jj < 4; ++jj)                   \
        bfr[jj] = LDB(S, KS, jj);                                        \
    }                                                                    \
    afr0 = LDA(S, KS, (IH) * 4 + 0);                                     \
    __builtin_amdgcn_s_setprio(1);                                       \
    afr1 = LDA(S, KS, (IH) * 4 + 1);                                     \
    CLUSTER((IH)*4+0, afr0);                                             \
    afr2 = LDA(S, KS, (IH) * 4 + 2);                                     \
    CLUSTER((IH)*4+1, afr1);                                             \
    afr3 = LDA(S, KS, (IH) * 4 + 3);                                     \
    CLUSTER((IH)*4+2, afr2);                                             \
    CLUSTER((IH)*4+3, afr3);                                             \
    __builtin_amdgcn_s_setprio(0);                                       \
    CFENCE();                                                            \
    if (TRAILVM) { WAITV(10); }                                          \
    CFENCE();                                                            \
    __builtin_amdgcn_s_barrier();                                        \
  } while (0)

  STAGE_B(0, 0, 0); STAGE_A(0, 0, 0); STAGE_B(0, 0, 1); STAGE_A(0, 0, 1);
  STAGE_B(1, 1, 0); STAGE_A(1, 1, 0); STAGE_B(1, 1, 1);
  WAITV(10);
  CFENCE();
  __builtin_amdgcn_s_barrier();

  for (int j = 0; j < NI; ++j) {
    const int t0 = 2 * j, t1 = 2 * j + 1;
    PHASE(0, 0, 0, 1, 0, STAGE_A(t1,     1, 1));  // p0
    PHASE(0, 0, 1, 0, 1, STAGE_B(t0 + 2, 0, 0));  // p1
    PHASE(0, 1, 0, 1, 0, STAGE_A(t0 + 2, 0, 0));  // p2
    PHASE(0, 1, 1, 0, 1, STAGE_B(t0 + 2, 0, 1));  // p3
    PHASE(1, 0, 0, 1, 0, STAGE_A(t0 + 2, 0, 1));  // p4
    PHASE(1, 0, 1, 0, 1, STAGE_B(t1 + 2, 1, 0));  // p5
    PHASE(1, 1, 0, 1, 0, STAGE_A(t1 + 2, 1, 0));  // p6
    PHASE(1, 1, 1, 0, 1, STAGE_B(t1 + 2, 1, 1));  // p7
  }

  WAITV(0);
  CFENCE();
  __builtin_amdgcn_s_barrier();

  float* panel = (float*)smem;      // 66560 B <= 128 KB
  const int q4 = (lane >> 4) * 4;
#pragma unroll 1
  for (int c = 0; c < 4; ++c) {
    if (wc == c) {
#pragma unroll
      for (int i = 0; i < 8; ++i)
#pragma unroll
        for (int jj = 0; jj < 4; ++jj)
#pragma unroll
          for (int r = 0; r < 4; ++r)
            panel[(wr * 128 + i * 16 + q4 + r) * 65 + jj * 16 + fr] =
                fmaxf(acc[i][jj][r], 0.f);
    }
    __builtin_amdgcn_s_barrier();
    CFENCE();
    {
      int col = tid & 63;
      int s = tid >> 6;
      float sum = 0.f;
#pragma unroll
      for (int r = 0; r < 30; ++r) sum += panel[(s * 30 + r) * 65 + col];
      int gseg = by * 8 + s;
      int gcol = bn0 + c * 64 + col;
      feat[(size_t)gseg * 2048 + gcol] = f2bf(sum * (1.f / 30.f));
    }
    CFENCE();
    __builtin_amdgcn_s_barrier();
  }
#undef PHASE
#undef CLUSTER
#undef LDA
#undef LDB
#undef STAGE_A
#undef STAGE_B
}

// ---------------------------------------------------------------------------
// GEMM2 split-K: grid (8,16,2). z-half computes K in [z*klen,(z+1)*klen) into
// its own f32 slab (deterministic, no atomics; slabs fully rewritten per
// call -> replay-safe). 256 blocks fill all 256 CUs (old gemm_bt<2> grid was
// 128 blocks = half the machine idle, ~35us for 8.2 GFLOP).
// ---------------------------------------------------------------------------
__global__ __launch_bounds__(256, 2)
void gemm2_splitk(const unsigned short* __restrict__ A,
                  const unsigned short* __restrict__ B,
                  float* __restrict__ slabs,
                  int Mv, int Nv, int ldK, int klen) {
  __shared__ __align__(16) unsigned short smem[2 * 128 * 64];
  unsigned short* As = smem;
  unsigned short* Bs = smem + 128 * 64;

  const int tid = threadIdx.x;
  const int lane = tid & 63;
  const int w = tid >> 6;
  const int wr = w >> 1, wc = w & 1;
  const int bm0 = blockIdx.y * 128;
  const int bn0 = blockIdx.x * 128;
  const int z = blockIdx.z;
  const unsigned short* Az = A + (size_t)z * klen;
  const unsigned short* Bz = B + (size_t)z * klen;
  float* slab = slabs + (size_t)z * 2000 * 1000;

  f32x4 acc[4][4];
#pragma unroll
  for (int i = 0; i < 4; ++i)
#pragma unroll
    for (int j = 0; j < 4; ++j) acc[i][j] = (f32x4){0.f, 0.f, 0.f, 0.f};

  const int fr = lane & 15;
  const int rsub = lane >> 3;
  const int k8 = (((lane & 7) ^ (lane >> 3)) * 8);

  for (int kt = 0; kt < klen; kt += 64) {
    __syncthreads();
#pragma unroll
    for (int j = 0; j < 4; ++j) {
      int g = w * 4 + j;
      int row = g * 8 + rsub;
      int gm = bm0 + row; if (gm >= Mv) gm = Mv - 1;
      gload_lds16(Az + (size_t)gm * ldK + kt + k8, As + g * 512);
      int gn = bn0 + row; if (gn >= Nv) gn = Nv - 1;
      gload_lds16(Bz + (size_t)gn * ldK + kt + k8, Bs + g * 512);
    }
    __syncthreads();
#pragma unroll
    for (int kk = 0; kk < 2; ++kk) {
      const int coff = ((((kk << 2) | (lane >> 4)) ^ (fr & 7)) * 8);
      short8 af[4], bfr[4];
#pragma unroll
      for (int i = 0; i < 4; ++i)
        af[i] = *(const short8*)(As + (wr * 64 + i * 16 + fr) * 64 + coff);
#pragma unroll
      for (int i = 0; i < 4; ++i)
        bfr[i] = *(const short8*)(Bs + (wc * 64 + i * 16 + fr) * 64 + coff);
#pragma unroll
      for (int i = 0; i < 4; ++i)
#pragma unroll
        for (int j = 0; j < 4; ++j)
          acc[i][j] = __builtin_amdgcn_mfma_f32_16x16x32_bf16(af[i], bfr[j], acc[i][j], 0, 0, 0);
    }
  }

  const int cr0 = (lane >> 4) * 4;
#pragma unroll
  for (int i = 0; i < 4; ++i)
#pragma unroll
    for (int j = 0; j < 4; ++j)
#pragma unroll
      for (int r = 0; r < 4; ++r) {
        int gm = bm0 + wr * 64 + i * 16 + cr0 + r;
        int gn = bn0 + wc * 64 + j * 16 + fr;
        if (gm < Mv && gn < Nv) slab[(size_t)gm * Nv + gn] = acc[i][j][r];
      }
}

// ---------------------------------------------------------------------------
// 128x128 kernel: fallback paths (MODE 0 fused, MODE 2 direct GEMM2).
// ---------------------------------------------------------------------------
#define BM 128
#define BN 128
#define BK 64

template<int MODE>
__global__ __launch_bounds__(256, 2)
void gemm_bt(const void* __restrict__ Ap, const void* __restrict__ Bp,
             void* __restrict__ Cp, int Mv, int Nv, int K, int mstep) {
  constexpr int LDK = (MODE == 0) ? 72 : 64;
  __shared__ __align__(16) unsigned short smem[2 * BM * LDK];
  unsigned short* As = smem;
  unsigned short* Bs = smem + BM * LDK;
  float* Cs = (float*)smem;

  const int tid = threadIdx.x;
  const int lane = tid & 63;
  const int w = tid >> 6;
  const int wr = w >> 1, wc = w & 1;
  const int bm0 = blockIdx.y * mstep;
  const int bn0 = blockIdx.x * BN;

  f32x4 acc[4][4];
#pragma unroll
  for (int i = 0; i < 4; ++i)
#pragma unroll
    for (int j = 0; j < 4; ++j) acc[i][j] = (f32x4){0.f, 0.f, 0.f, 0.f};

  const int fr = lane & 15;
  const int ko = (lane >> 4) * 8;

  for (int kt = 0; kt < K; kt += BK) {
    __syncthreads();
    if constexpr (MODE == 0) {
      const float* A = (const float*)Ap;
      const float* B = (const float*)Bp;
      const int r0 = tid >> 4, kq = tid & 15;
#pragma unroll
      for (int i = 0; i < 8; ++i) {
        int row = i * 16 + r0;
        {
          int gm = bm0 + row;
          f32x4 v = {0.f, 0.f, 0.f, 0.f};
          if (gm < Mv) v = *(const f32x4*)(A + (size_t)gm * K + kt + kq * 4);
          *(unsigned long long*)(As + row * LDK + kq * 4) = pack4(v);
        }
        {
          int gn = bn0 + row;
          f32x4 v = {0.f, 0.f, 0.f, 0.f};
          if (gn < Nv) v = *(const f32x4*)(B + (size_t)gn * K + kt + kq * 4);
          *(unsigned long long*)(Bs + row * LDK + kq * 4) = pack4(v);
        }
      }
    } else {
      const unsigned short* A = (const unsigned short*)Ap;
      const unsigned short* B = (const unsigned short*)Bp;
      const int rsub = lane >> 3;
      const int k8 = (((lane & 7) ^ (lane >> 3)) * 8);
#pragma unroll
      for (int j = 0; j < 4; ++j) {
        int g = w * 4 + j;
        int row = g * 8 + rsub;
        int gm = bm0 + row; if (gm >= Mv) gm = Mv - 1;
        gload_lds16(A + (size_t)gm * K + kt + k8, As + g * 512);
        int gn = bn0 + row; if (gn >= Nv) gn = Nv - 1;
        gload_lds16(B + (size_t)gn * K + kt + k8, Bs + g * 512);
      }
    }
    __syncthreads();
#pragma unroll
    for (int kk = 0; kk < 2; ++kk) {
      const int coffA = (MODE == 0) ? (kk * 32 + ko)
                                    : ((((kk << 2) | (lane >> 4)) ^ (fr & 7)) * 8);
      short8 af[4], bfr[4];
#pragma unroll
      for (int i = 0; i < 4; ++i)
        af[i] = *(const short8*)(As + (wr * 64 + i * 16 + fr) * LDK + coffA);
#pragma unroll
      for (int i = 0; i < 4; ++i)
        bfr[i] = *(const short8*)(Bs + (wc * 64 + i * 16 + fr) * LDK + coffA);
#pragma unroll
      for (int i = 0; i < 4; ++i)
#pragma unroll
        for (int j = 0; j < 4; ++j)
          acc[i][j] = __builtin_amdgcn_mfma_f32_16x16x32_bf16(af[i], bfr[j], acc[i][j], 0, 0, 0);
    }
  }
  __syncthreads();

  if constexpr (MODE != 2) {
    unsigned short* feat = (unsigned short*)Cp;
    const int cr0 = (lane >> 4) * 4;
#pragma unroll
    for (int half = 0; half < 2; ++half) {
      if (wc == half) {
#pragma unroll
        for (int i = 0; i < 4; ++i)
#pragma unroll
          for (int j = 0; j < 4; ++j)
#pragma unroll
            for (int r = 0; r < 4; ++r)
              Cs[(wr * 64 + i * 16 + cr0 + r) * 64 + j * 16 + fr] =
                  fmaxf(acc[i][j][r], 0.f);
      }
      __syncthreads();
      {
        int col = tid & 63;
        int s = tid >> 6;
        float sum = 0.f;
#pragma unroll
        for (int r = 0; r < 30; ++r) sum += Cs[(s * 30 + r) * 64 + col];
        int gseg = blockIdx.y * 4 + s;
        int gcol = bn0 + half * 64 + col;
        feat[(size_t)gseg * 2048 + gcol] = f2bf(sum * (1.f / 30.f));
      }
      __syncthreads();
    }
  } else {
    float* out = (float*)Cp;
    const int cr0 = (lane >> 4) * 4;
#pragma unroll
    for (int i = 0; i < 4; ++i)
#pragma unroll
      for (int j = 0; j < 4; ++j)
#pragma unroll
        for (int r = 0; r < 4; ++r) {
          int gm = bm0 + wr * 64 + i * 16 + cr0 + r;
          int gn = bn0 + wc * 64 + j * 16 + fr;
          if (gm < Mv && gn < Nv) out[(size_t)gm * Nv + gn] = acc[i][j][r];
        }
  }
}

extern "C" void kernel_launch(void* const* d_in, const int* in_sizes, int n_in,
                              void* d_out, int out_size, void* d_ws, size_t ws_size,
                              hipStream_t stream) {
  const float* x    = (const float*)d_in[0];
  const float* W1   = (const float*)d_in[2];
  const float* Wlin = (const float*)d_in[4];
  float* out = (float*)d_out;

  const int T = 60000, DIN = 1024, E = 2048, C = 1000, S = 2000;
  char* ws = (char*)d_ws;
  const size_t off_feat = 0;
  const size_t off_wsum = (size_t)S * E * 2;
  const size_t off_w1b  = off_wsum + (size_t)C * E * 2;
  const size_t off_xb   = off_w1b + (size_t)E * DIN * 2;
  const size_t off_slab = off_xb + (size_t)T * DIN * 2;     // ~139.4 MB
  const size_t slab_bytes = (size_t)2 * S * C * 4;          // 16 MB
  const size_t need_gemm1 = off_slab;                        // xb path
  const size_t need_slabs = off_slab + slab_bytes;           // ~155.4 MB

  unsigned short* feat = (unsigned short*)(ws + off_feat);
  unsigned short* wsum = (unsigned short*)(ws + off_wsum);

  if (ws_size >= need_gemm1) {
    unsigned short* w1b = (unsigned short*)(ws + off_w1b);
    unsigned short* xb  = (unsigned short*)(ws + off_xb);
    prep_w<<<dim3((1000 * 512 + 2048 * 256 + 255) / 256), dim3(256), 0, stream>>>(
        Wlin, W1, wsum, w1b);
    int nx4 = T * DIN / 4;
    cvt_f32_bf16<<<dim3((nx4 + 255) / 256), dim3(256), 0, stream>>>(x, xb, nx4);
    gemm256_pool<<<dim3(2000), dim3(512), 0, stream>>>(xb, w1b, feat, T, DIN);
  } else {
    prep_wsum<<<dim3((C * E / 4 + 255) / 256), dim3(256), 0, stream>>>(Wlin, wsum);
    gemm_bt<0><<<dim3(16, 500), dim3(256), 0, stream>>>(x, W1, feat, T, E, DIN, 120);
  }

  if (ws_size >= need_slabs) {
    float* slabs = (float*)(ws + off_slab);
    gemm2_splitk<<<dim3(8, 16, 2), dim3(256), 0, stream>>>(feat, wsum, slabs,
                                                           S, C, E, E / 2);
    int n4 = S * C / 4;
    reduce2<<<dim3((n4 + 255) / 256), dim3(256), 0, stream>>>(
        slabs, slabs + (size_t)S * C, out, n4);
  } else {
    gemm_bt<2><<<dim3(8, 16), dim3(256), 0, stream>>>(feat, wsum, out, S, C, E, 128);
  }
}